// Round 6
// baseline (15992.975 us; speedup 1.0000x reference)
//
#include <hip/hip_runtime.h>

#define NG 4096
#define NP 512
#define BSZ 128
#define NT 100

typedef unsigned short u16;
typedef _Float16 f16;
typedef __attribute__((ext_vector_type(8))) _Float16 half8;
typedef __attribute__((ext_vector_type(4))) _Float16 half4v;
typedef __attribute__((ext_vector_type(16))) float f32x16;

__device__ inline f32x16 mfma16(half8 a, half8 b, f32x16 c) {
  return __builtin_amdgcn_mfma_f32_32x32x16_f16(a, b, c, 0, 0, 0);
}
__device__ __forceinline__ void gload16(const void* g, void* l) {
  __builtin_amdgcn_global_load_lds(
      (const __attribute__((address_space(1))) void*)g,
      (__attribute__((address_space(3))) void*)l, 16, 0, 0);
}

// ---------------- prep: f32 -> fp16 ----------------
__global__ __launch_bounds__(256) void conv_f16(
    const float* __restrict__ src, f16* __restrict__ dst, int n4)
{
  int i = blockIdx.x * 256 + threadIdx.x;
  if (i >= n4) return;
  const float4 x = ((const float4*)src)[i];
  half4v h = { (f16)x.x, (f16)x.y, (f16)x.z, (f16)x.w };
  *(half4v*)&dst[(size_t)i * 4] = h;
}

__global__ void bar_init(unsigned* bar) {
  if (threadIdx.x < 16) bar[threadIdx.x] = 0u;
}

// ---------------- K-split fp16 GEMM (encode only; verified r5) ----------------
__global__ __launch_bounds__(256, 2) void gemm_ksplit(
    const f16* __restrict__ bmat, const f16* __restrict__ amat,
    f16* __restrict__ part, int krow, int kblk, int nch)
{
  __shared__ __align__(128) char lds[2 * 32768];
  const int tid = threadIdx.x;
  const int w = tid >> 6, lane = tid & 63;
  const int wm = w & 1, wn = w >> 1;
  const int l31 = lane & 31, hi = lane >> 5;
  const int n0 = blockIdx.y * 128;
  const size_t krb = (size_t)krow * 2;

  const int srow = tid >> 3, su = tid & 7;
  const char* gA = (const char*)amat;
  const char* gB = (const char*)bmat + (size_t)n0 * krb;

  f32x16 acc[2][2] = {};

  auto stage = [&](int buf, int c) {
    const size_t kbase = (size_t)((blockIdx.x * kblk + c * 64) * 2);
    char* lb = lds + buf * 32768;
    #pragma unroll
    for (int i = 0; i < 4; ++i) {
      const int r = i * 32 + srow;
      const size_t src = (size_t)r * krb + kbase + ((su ^ (r & 7)) * 16);
      gload16(gA + src, lb + r * 128 + su * 16);
      gload16(gB + src, lb + 16384 + r * 128 + su * 16);
    }
  };
  auto compute = [&](int buf) {
    const char* bA = lds + buf * 32768;
    const char* bB = bA + 16384;
    const int swr = (l31 & 7) << 4;
    #pragma unroll
    for (int kk = 0; kk < 4; ++kk) {
      const int bc = (kk * 32 + (hi << 4)) ^ swr;
      half8 a0 = *(const half8*)(bA + (wm * 64 + l31) * 128 + bc);
      half8 a1 = *(const half8*)(bA + (wm * 64 + 32 + l31) * 128 + bc);
      half8 b0 = *(const half8*)(bB + (wn * 64 + l31) * 128 + bc);
      half8 b1 = *(const half8*)(bB + (wn * 64 + 32 + l31) * 128 + bc);
      acc[0][0] = mfma16(a0, b0, acc[0][0]);
      acc[0][1] = mfma16(a0, b1, acc[0][1]);
      acc[1][0] = mfma16(a1, b0, acc[1][0]);
      acc[1][1] = mfma16(a1, b1, acc[1][1]);
    }
  };

  stage(0, 0);
  __syncthreads();
  #pragma unroll 1
  for (int c = 0; c < nch; ++c) {
    if (c + 1 < nch) stage((c + 1) & 1, c + 1);
    compute(c & 1);
    __syncthreads();
  }

  f16* exh = (f16*)lds;
  #pragma unroll
  for (int mf = 0; mf < 2; ++mf)
    #pragma unroll
    for (int nf = 0; nf < 2; ++nf)
      #pragma unroll
      for (int q = 0; q < 16; ++q) {
        const int row = wm * 64 + mf * 32 + (q & 3) + 8 * (q >> 2) + 4 * hi;
        const int col = wn * 64 + nf * 32 + l31;
        exh[row * 128 + col] = (f16)acc[mf][nf][q];
      }
  __syncthreads();
  f16* po = part + (size_t)blockIdx.x * (BSZ * NG) + n0;
  #pragma unroll
  for (int i = 0; i < 8; ++i) {
    const int flat = i * 256 + tid;
    const int r = flat >> 4, uu = flat & 15;
    *(half8*)(po + (size_t)r * NG + uu * 8) = *(const half8*)(exh + r * 128 + uu * 8);
  }
}

// sum nsets fp16 partials (+ optional bias/relu) -> f16  (encode epilogue)
__global__ __launch_bounds__(256) void reduce_kernel(
    const f16* __restrict__ part, const float* __restrict__ v,
    const float* __restrict__ wih, f16* __restrict__ hout,
    int t, int nsets, int dobias)
{
  const int i = blockIdx.x * 256 + threadIdx.x;
  const int b = i >> 9;
  const int gi = (i & 511) * 8;
  const half8* p = (const half8*)part + (((size_t)b * NG + gi) >> 3);
  float s[8];
  half8 q0 = p[0];
  #pragma unroll
  for (int j = 0; j < 8; ++j) s[j] = (float)q0[j];
  #pragma unroll 1
  for (int k = 1; k < nsets; ++k) {
    half8 q = p[(size_t)k * (BSZ * NG / 8)];
    #pragma unroll
    for (int j = 0; j < 8; ++j) s[j] += (float)q[j];
  }
  half8 h;
  if (dobias) {
    const float2 vb = *(const float2*)&v[((size_t)b * NT + t) * 2];
    const float4* wr = (const float4*)(wih + (size_t)gi * 2);
    #pragma unroll
    for (int j2 = 0; j2 < 4; ++j2) {
      const float4 ww = wr[j2];
      h[j2 * 2]     = (f16)fmaxf(s[j2 * 2]     + vb.x * ww.x + vb.y * ww.y, 0.f);
      h[j2 * 2 + 1] = (f16)fmaxf(s[j2 * 2 + 1] + vb.x * ww.z + vb.y * ww.w, 0.f);
    }
  } else {
    #pragma unroll
    for (int j = 0; j < 8; ++j) h[j] = (f16)s[j];
  }
  *(half8*)&hout[(size_t)b * NG + gi] = h;
}

// ---------------- persistent recurrent kernel ----------------
// 256 blocks x 512 thr, 1 block/CU (128 KB LDS forces exclusivity).
// Block (ks=bid&7, nb=bid>>3): output tile 128 x [nb*128,+128), k-slice
// [ks*512,+512). B = Whh chunk lives in 128 VGPR/lane for all 100 steps.
// Wave w: wm=w&1 (M64), wn=(w>>1)&1 (N64), kg=w>>2 (K256 half).
// Per step: stage A(h[t-1] slice, XOR-swz) -> MFMA -> f16 partial (16 sets,
// LDS-bounce coalesced) -> gridbar -> 4-elem/thread reduce+bias+relu ->
// hs[t] -> gridbar.
__device__ __forceinline__ void gridbar(unsigned* bar, int ks, int tid) {
  __threadfence();
  __syncthreads();
  if (tid == 0) {
    unsigned g = __hip_atomic_load(&bar[9], __ATOMIC_RELAXED, __HIP_MEMORY_SCOPE_AGENT);
    unsigned a = __hip_atomic_fetch_add(&bar[ks], 1u, __ATOMIC_ACQ_REL, __HIP_MEMORY_SCOPE_AGENT);
    if (a == 31u) {
      __hip_atomic_store(&bar[ks], 0u, __ATOMIC_RELAXED, __HIP_MEMORY_SCOPE_AGENT);
      unsigned m = __hip_atomic_fetch_add(&bar[8], 1u, __ATOMIC_ACQ_REL, __HIP_MEMORY_SCOPE_AGENT);
      if (m == 7u) {
        __hip_atomic_store(&bar[8], 0u, __ATOMIC_RELAXED, __HIP_MEMORY_SCOPE_AGENT);
        __hip_atomic_store(&bar[9], g + 1u, __ATOMIC_RELEASE, __HIP_MEMORY_SCOPE_AGENT);
      } else {
        while (__hip_atomic_load(&bar[9], __ATOMIC_RELAXED, __HIP_MEMORY_SCOPE_AGENT) == g)
          __builtin_amdgcn_s_sleep(1);
      }
    } else {
      while (__hip_atomic_load(&bar[9], __ATOMIC_RELAXED, __HIP_MEMORY_SCOPE_AGENT) == g)
        __builtin_amdgcn_s_sleep(1);
    }
    (void)__hip_atomic_load(&bar[9], __ATOMIC_ACQUIRE, __HIP_MEMORY_SCOPE_AGENT);
  }
  __syncthreads();
}

__global__ __launch_bounds__(512, 2) void rnn_persist(
    const f16* __restrict__ whh16, f16* __restrict__ hs0,
    f16* __restrict__ part, const float* __restrict__ v,
    const float* __restrict__ wih, unsigned* __restrict__ bar)
{
  __shared__ __align__(128) char lds[131072];
  const int tid = threadIdx.x;
  const int bid = blockIdx.x;
  const int ks = bid & 7;
  const int nb = bid >> 3;
  const int n0 = nb * 128;
  const int w = tid >> 6, lane = tid & 63;
  const int l31 = lane & 31, hi = lane >> 5;
  const int wm = w & 1, wn = (w >> 1) & 1, kg = w >> 2;
  const size_t HS = (size_t)BSZ * NG;   // f16 elems per h slot

  // ---- B preload into registers (one-time, 33.5 MB total) ----
  half8 Breg[2][16];
  {
    const f16* bp = whh16 + (size_t)(n0 + wn * 64 + l31) * NG
                  + ks * 512 + kg * 256 + hi * 8;
    #pragma unroll
    for (int nf = 0; nf < 2; ++nf)
      #pragma unroll
      for (int kk = 0; kk < 16; ++kk)
        Breg[nf][kk] = *(const half8*)(bp + (size_t)nf * 32 * NG + kk * 16);
  }

  // ---- reduce-phase per-thread constants ----
  const int eb = (bid * 512 + tid) * 4;  // output elem base (0..524284)
  const int rb = eb >> 12;               // batch row
  const int rc = eb & 4095;              // col
  const float4 wA = *(const float4*)(wih + (size_t)rc * 2);
  const float4 wB = *(const float4*)(wih + (size_t)rc * 2 + 4);

  const int ar0 = wm * 64 + l31;
  const int ar1 = ar0 + 32;
  const int sw0 = (ar0 & 7);             // == l31&7 for both ar0/ar1

  #pragma unroll 1
  for (int i = 1; i <= NT; ++i) {
    // ---- stage A slice: rows 0..127, k in [ks*512,+512), swz on source ----
    {
      const char* gsrc = (const char*)(hs0 + (size_t)(i - 1) * HS);
      #pragma unroll
      for (int r = 0; r < 16; ++r) {
        const int row = w * 16 + r;
        const size_t go = (size_t)row * (NG * 2) + (size_t)ks * 1024
                        + (size_t)(((lane ^ (row & 7)) & 63) * 16);
        gload16(gsrc + go, lds + row * 1024);
      }
    }
    __syncthreads();

    // ---- MFMA: 64 per wave ----
    f32x16 a00 = {}, a01 = {}, a10 = {}, a11 = {};
    #pragma unroll
    for (int kk = 0; kk < 16; ++kk) {
      const int u = kg * 32 + kk * 2 + hi;
      half8 af0 = *(const half8*)(lds + ar0 * 1024 + ((u ^ sw0) * 16));
      half8 af1 = *(const half8*)(lds + ar1 * 1024 + ((u ^ sw0) * 16));
      a00 = mfma16(af0, Breg[0][kk], a00);
      a01 = mfma16(af0, Breg[1][kk], a01);
      a10 = mfma16(af1, Breg[0][kk], a10);
      a11 = mfma16(af1, Breg[1][kk], a11);
    }
    __syncthreads();

    // ---- bounce partials to LDS (kg region), coalesced copy out ----
    {
      f16* bl = (f16*)lds + kg * 16384;
      #pragma unroll
      for (int q = 0; q < 16; ++q) {
        const int row0 = wm * 64 + (q & 3) + 8 * (q >> 2) + 4 * hi;
        const int col0 = wn * 64 + l31;
        bl[row0 * 128 + col0]              = (f16)a00[q];
        bl[row0 * 128 + col0 + 32]         = (f16)a01[q];
        bl[(row0 + 32) * 128 + col0]       = (f16)a10[q];
        bl[(row0 + 32) * 128 + col0 + 32]  = (f16)a11[q];
      }
    }
    __syncthreads();
    {
      char* pbase = (char*)part;
      #pragma unroll
      for (int it = 0; it < 8; ++it) {
        const int q = it * 512 + tid;
        const int kgq = q >> 11;
        const int qk = q & 2047;
        const int m = qk >> 4, uu = qk & 15;
        const size_t dst = (size_t)(ks * 2 + kgq) * 1048576
                         + (size_t)m * 8192 + (size_t)n0 * 2 + uu * 16;
        *(half8*)(pbase + dst) = *(const half8*)(lds + kgq * 32768 + m * 256 + uu * 16);
      }
    }

    gridbar(bar, ks, tid);

    // ---- reduce 16 sets + bias + relu -> hs[i] ----
    {
      const char* pbase = (const char*)part + (size_t)eb * 2;
      float s0 = 0.f, s1 = 0.f, s2 = 0.f, s3 = 0.f;
      #pragma unroll
      for (int sx = 0; sx < 16; ++sx) {
        half4v q = *(const half4v*)(pbase + (size_t)sx * 1048576);
        s0 += (float)q[0]; s1 += (float)q[1]; s2 += (float)q[2]; s3 += (float)q[3];
      }
      const float2 vb = *(const float2*)(v + ((size_t)rb * NT + (i - 1)) * 2);
      half4v h;
      h[0] = (f16)fmaxf(s0 + vb.x * wA.x + vb.y * wA.y, 0.f);
      h[1] = (f16)fmaxf(s1 + vb.x * wA.z + vb.y * wA.w, 0.f);
      h[2] = (f16)fmaxf(s2 + vb.x * wB.x + vb.y * wB.y, 0.f);
      h[3] = (f16)fmaxf(s3 + vb.x * wB.z + vb.y * wB.w, 0.f);
      *(half4v*)(hs0 + (size_t)i * HS + eb) = h;
    }

    gridbar(bar, ks, tid);
  }
}

// ---------------- decode + fused log_softmax (r4 version, 114 us) ----------------
__global__ __launch_bounds__(512, 2) void decode_kernel(
    const f16* __restrict__ hs, const f16* __restrict__ wdec16,
    float* __restrict__ out)
{
  __shared__ __align__(128) char lds[2 * 73728];
  __shared__ float redm[8][64];
  __shared__ float reds[8][64];
  __shared__ float gLS[64];
  const int tid = threadIdx.x;
  const int w = tid >> 6, lane = tid & 63;
  const int l31 = lane & 31, hi = lane >> 5;
  const int r0 = blockIdx.x * 64;

  const int lrow8 = lane >> 3;
  const int swz = ((lane & 7) ^ lrow8) * 16;
  const char* gA = (const char*)(hs + (size_t)r0 * NG);
  const char* gB = (const char*)wdec16;

  f32x16 acc[2][2] = {};

  auto stage = [&](int buf, int c) {
    const size_t kb = (size_t)(c * 128) + swz;
    char* lb = lds + buf * 73728;
    gload16(gA + (size_t)(w * 8 + lrow8) * (NG * 2) + kb, lb + w * 1024);
    #pragma unroll
    for (int j = 0; j < 8; ++j) {
      const int r = w * 64 + j * 8;
      gload16(gB + (size_t)(r + lrow8) * (NG * 2) + kb, lb + 8192 + r * 128);
    }
  };
  auto compute = [&](int buf) {
    const char* bA = lds + buf * 73728;
    const char* bB = bA + 8192;
    const int swr = (lane & 7) << 4;
    #pragma unroll
    for (int kk = 0; kk < 4; ++kk) {
      const int bc = (kk * 32 + (hi << 4)) ^ swr;
      half8 a0 = *(const half8*)(bA + l31 * 128 + bc);
      half8 a1 = *(const half8*)(bA + (32 + l31) * 128 + bc);
      half8 b0 = *(const half8*)(bB + (w * 64 + l31) * 128 + bc);
      half8 b1 = *(const half8*)(bB + (w * 64 + 32 + l31) * 128 + bc);
      acc[0][0] = mfma16(a0, b0, acc[0][0]);
      acc[0][1] = mfma16(a0, b1, acc[0][1]);
      acc[1][0] = mfma16(a1, b0, acc[1][0]);
      acc[1][1] = mfma16(a1, b1, acc[1][1]);
    }
  };

  stage(0, 0);
  __syncthreads();
  #pragma unroll 1
  for (int c = 0; c < 64; ++c) {
    if (c < 63) stage((c + 1) & 1, c + 1);
    compute(c & 1);
    __syncthreads();
  }

  #pragma unroll
  for (int mf = 0; mf < 2; ++mf) {
    #pragma unroll
    for (int q = 0; q < 16; ++q) {
      float m = fmaxf(acc[mf][0][q], acc[mf][1][q]);
      #pragma unroll
      for (int d = 1; d < 32; d <<= 1) m = fmaxf(m, __shfl_xor(m, d));
      if (l31 == q) redm[w][mf * 32 + (q & 3) + 8 * (q >> 2) + 4 * hi] = m;
    }
  }
  __syncthreads();
  if (tid < 64) {
    float M = redm[0][tid];
    #pragma unroll
    for (int ww = 1; ww < 8; ++ww) M = fmaxf(M, redm[ww][tid]);
    gLS[tid] = M;
  }
  __syncthreads();
  #pragma unroll
  for (int mf = 0; mf < 2; ++mf) {
    #pragma unroll
    for (int q = 0; q < 16; ++q) {
      const int rl = mf * 32 + (q & 3) + 8 * (q >> 2) + 4 * hi;
      const float M = gLS[rl];
      float e = __expf(acc[mf][0][q] - M) + __expf(acc[mf][1][q] - M);
      #pragma unroll
      for (int d = 1; d < 32; d <<= 1) e += __shfl_xor(e, d);
      if (l31 == q) reds[w][rl] = e;
    }
  }
  __syncthreads();
  if (tid < 64) {
    float S = reds[0][tid];
    #pragma unroll
    for (int ww = 1; ww < 8; ++ww) S += reds[ww][tid];
    gLS[tid] = gLS[tid] + __logf(S);
  }
  __syncthreads();
  #pragma unroll
  for (int mf = 0; mf < 2; ++mf) {
    #pragma unroll
    for (int q = 0; q < 16; ++q) {
      const int rl = mf * 32 + (q & 3) + 8 * (q >> 2) + 4 * hi;
      const int r = r0 + rl;
      const int tt = r >> 7, b = r & 127;
      const float lg = gLS[rl];
      float* orow = out + ((size_t)b * NT + tt) * NP + w * 64 + l31;
      orow[0]  = acc[mf][0][q] - lg;
      orow[32] = acc[mf][1][q] - lg;
    }
  }
}

// ---------------- host ----------------

extern "C" void kernel_launch(void* const* d_in, const int* in_sizes, int n_in,
                              void* d_out, int out_size, void* d_ws, size_t ws_size,
                              hipStream_t stream)
{
  const float* v    = (const float*)d_in[0];
  const float* p0   = (const float*)d_in[1];
  const float* wenc = (const float*)d_in[2];
  const float* wih  = (const float*)d_in[3];
  const float* whh  = (const float*)d_in[4];
  const float* wdec = (const float*)d_in[5];
  float* out = (float*)d_out;
  char* ws = (char*)d_ws;

  f16* whh16  = (f16*)(ws);                    // 33,554,432 B
  f16* wdec16 = (f16*)(ws + 33554432);         //  4,194,304 B
  f16* wenc16 = (f16*)(ws + 37748736);         //  4,194,304 B
  f16* p016   = (f16*)(ws + 41943040);         //    131,072 B
  unsigned* bar = (unsigned*)(ws + 42074112);  //      4,096 B
  f16* part   = (f16*)(ws + 42078208);         // 16,777,216 B (16 sets)
  f16* hs     = (f16*)(ws + 58855424);         // 101 x 1,048,576 B (slots 0..100)
  const size_t HS = (size_t)BSZ * NG;

  conv_f16<<<dim3(16384), dim3(256), 0, stream>>>(whh, whh16, 4194304);
  conv_f16<<<dim3(2048), dim3(256), 0, stream>>>(wdec, wdec16, 524288);
  conv_f16<<<dim3(2048), dim3(256), 0, stream>>>(wenc, wenc16, 524288);
  conv_f16<<<dim3(64), dim3(256), 0, stream>>>(p0, p016, 16384);
  bar_init<<<dim3(1), dim3(64), 0, stream>>>(bar);

  // encode: h0 = p0 @ Wenc^T  (K=512, KS=2) -> hs slot 0
  gemm_ksplit<<<dim3(2, 32), dim3(256), 0, stream>>>(wenc16, p016, part, NP, 256, 4);
  reduce_kernel<<<dim3(256), dim3(256), 0, stream>>>(part, v, wih, hs, 0, 2, 0);

  // 100 recurrent steps in ONE persistent kernel
  rnn_persist<<<dim3(256), dim3(512), 0, stream>>>(whh16, hs, part, v, wih, bar);

  // decode states 1..100
  decode_kernel<<<dim3(200), dim3(512), 0, stream>>>(hs + HS, wdec16, out);
}

// Round 7
// 1853.120 us; speedup vs baseline: 8.6303x; 8.6303x over previous
//
#include <hip/hip_runtime.h>

#define NG 4096
#define NP 512
#define BSZ 128
#define NT 100
#define KS 16
#define KBLK 256

typedef _Float16 f16;
typedef __attribute__((ext_vector_type(8))) _Float16 half8;
typedef __attribute__((ext_vector_type(4))) _Float16 half4v;
typedef __attribute__((ext_vector_type(16))) float f32x16;

__device__ inline f32x16 mfma16(half8 a, half8 b, f32x16 c) {
  return __builtin_amdgcn_mfma_f32_32x32x16_f16(a, b, c, 0, 0, 0);
}
__device__ __forceinline__ void gload16(const void* g, void* l) {
  __builtin_amdgcn_global_load_lds(
      (const __attribute__((address_space(1))) void*)g,
      (__attribute__((address_space(3))) void*)l, 16, 0, 0);
}

// ---------------- prep: all f32 -> fp16 conversions in ONE launch ----------------
__global__ __launch_bounds__(256) void conv_all(
    const float* __restrict__ whh, const float* __restrict__ wdec,
    const float* __restrict__ wenc, const float* __restrict__ p0,
    f16* __restrict__ whh16, f16* __restrict__ wdec16,
    f16* __restrict__ wenc16, f16* __restrict__ p016)
{
  int i = blockIdx.x * 256 + threadIdx.x;
  const float* src; f16* dst; int off;
  if (i < 4194304)      { src = whh;  dst = whh16;  off = 0; }
  else if (i < 4718592) { src = wdec; dst = wdec16; off = 4194304; }
  else if (i < 5242880) { src = wenc; dst = wenc16; off = 4718592; }
  else if (i < 5259264) { src = p0;   dst = p016;   off = 5242880; }
  else return;
  const int j = i - off;
  const float4 x = ((const float4*)src)[j];
  half4v h = { (f16)x.x, (f16)x.y, (f16)x.z, (f16)x.w };
  *(half4v*)&dst[(size_t)j * 4] = h;
}

// ---------------- K-split fp16 GEMM (r3 structure, verified fastest) ----------------
// part[bx][m][n] = sum_{k in slice bx} A[m][k] * B[n][k]
// 256 thr = 4 waves (2M x 2N), wave tile 64x64, 32x32x16 MFMA, 2 blocks/CU.
// LDS dbuf 2 x (A 16K + B 16K); XOR swizzle applied on GLOBAL source (rule #21),
// LDS linear, read side same XOR. Direct scattered f16 partial store (r3).
__global__ __launch_bounds__(256, 2) void gemm_ksplit(
    const f16* __restrict__ bmat, const f16* __restrict__ amat,
    f16* __restrict__ part, int krow, int nch)
{
  __shared__ __align__(128) char lds[2 * 32768];
  const int tid = threadIdx.x;
  const int w = tid >> 6, lane = tid & 63;
  const int wm = w & 1, wn = w >> 1;
  const int l31 = lane & 31, hi = lane >> 5;
  const int n0 = blockIdx.y * 128;
  const int k0 = blockIdx.x * KBLK;
  const size_t krb = (size_t)krow * 2;

  const int lrow8 = lane >> 3;
  const int swz = ((lane & 7) ^ lrow8) * 16;
  const char* gA = (const char*)amat;
  const char* gB = (const char*)bmat + (size_t)n0 * krb;

  f32x16 acc[2][2] = {};

  auto stage = [&](int buf, int c) {
    const size_t kb = (size_t)((k0 + c * 64) * 2) + swz;
    char* lb = lds + buf * 32768;
    #pragma unroll
    for (int j = 0; j < 4; ++j) {
      const int r = w * 32 + j * 8;
      gload16(gA + (size_t)(r + lrow8) * krb + kb, lb + r * 128);
      gload16(gB + (size_t)(r + lrow8) * krb + kb, lb + 16384 + r * 128);
    }
  };
  auto compute = [&](int buf) {
    const char* bA = lds + buf * 32768;
    const char* bB = bA + 16384;
    const int swr = (lane & 7) << 4;
    #pragma unroll
    for (int kk = 0; kk < 4; ++kk) {
      const int bc = (kk * 32 + (hi << 4)) ^ swr;
      half8 a0 = *(const half8*)(bA + (wm * 64 + l31) * 128 + bc);
      half8 a1 = *(const half8*)(bA + (wm * 64 + 32 + l31) * 128 + bc);
      half8 b0 = *(const half8*)(bB + (wn * 64 + l31) * 128 + bc);
      half8 b1 = *(const half8*)(bB + (wn * 64 + 32 + l31) * 128 + bc);
      acc[0][0] = mfma16(a0, b0, acc[0][0]);
      acc[0][1] = mfma16(a0, b1, acc[0][1]);
      acc[1][0] = mfma16(a1, b0, acc[1][0]);
      acc[1][1] = mfma16(a1, b1, acc[1][1]);
    }
  };

  stage(0, 0);
  __syncthreads();
  #pragma unroll 1
  for (int c = 0; c < nch; ++c) {
    if (c + 1 < nch) stage((c + 1) & 1, c + 1);
    compute(c & 1);
    __syncthreads();
  }

  // C/D 32x32 frag: col = lane&31, row = (q&3)+8*(q>>2)+4*(lane>>5) [verified]
  f16* po = part + (size_t)blockIdx.x * (BSZ * NG);
  #pragma unroll
  for (int mf = 0; mf < 2; ++mf) {
    #pragma unroll
    for (int q = 0; q < 16; ++q) {
      const int row = wm * 64 + mf * 32 + (q & 3) + 8 * (q >> 2) + 4 * hi;
      #pragma unroll
      for (int nf = 0; nf < 2; ++nf) {
        const int col = n0 + wn * 64 + nf * 32 + l31;
        po[(size_t)row * NG + col] = (f16)acc[mf][nf][q];
      }
    }
  }
}

// sum nsets fp16 partials (+ optional vin bias + relu) -> f16
__global__ __launch_bounds__(256) void reduce_kernel(
    const f16* __restrict__ part, const float* __restrict__ v,
    const float* __restrict__ wih, f16* __restrict__ hout,
    int t, int nsets, int dobias)
{
  const int i = blockIdx.x * 256 + threadIdx.x;   // 65536 threads x 8 elems
  const int b = i >> 9;
  const int gi = (i & 511) * 8;
  const half8* p = (const half8*)part + (((size_t)b * NG + gi) >> 3);
  float s[8];
  half8 q0 = p[0];
  #pragma unroll
  for (int j = 0; j < 8; ++j) s[j] = (float)q0[j];
  #pragma unroll 1
  for (int k = 1; k < nsets; ++k) {
    half8 q = p[(size_t)k * (BSZ * NG / 8)];
    #pragma unroll
    for (int j = 0; j < 8; ++j) s[j] += (float)q[j];
  }
  half8 h;
  if (dobias) {
    const float2 vb = *(const float2*)&v[((size_t)b * NT + t) * 2];
    const float4* wr = (const float4*)(wih + (size_t)gi * 2);
    #pragma unroll
    for (int j2 = 0; j2 < 4; ++j2) {
      const float4 ww = wr[j2];
      h[j2 * 2]     = (f16)fmaxf(s[j2 * 2]     + vb.x * ww.x + vb.y * ww.y, 0.f);
      h[j2 * 2 + 1] = (f16)fmaxf(s[j2 * 2 + 1] + vb.x * ww.z + vb.y * ww.w, 0.f);
    }
  } else {
    #pragma unroll
    for (int j = 0; j < 8; ++j) h[j] = (f16)s[j];
  }
  *(half8*)&hout[(size_t)b * NG + gi] = h;
}

// ---------------- decode + fused log_softmax (r4 version, 114 us measured) ----------------
__global__ __launch_bounds__(512, 2) void decode_kernel(
    const f16* __restrict__ hs, const f16* __restrict__ wdec16,
    float* __restrict__ out)
{
  __shared__ __align__(128) char lds[2 * 73728];
  __shared__ float redm[8][64];
  __shared__ float reds[8][64];
  __shared__ float gLS[64];
  const int tid = threadIdx.x;
  const int w = tid >> 6, lane = tid & 63;
  const int l31 = lane & 31, hi = lane >> 5;
  const int r0 = blockIdx.x * 64;

  const int lrow8 = lane >> 3;
  const int swz = ((lane & 7) ^ lrow8) * 16;
  const char* gA = (const char*)(hs + (size_t)r0 * NG);
  const char* gB = (const char*)wdec16;

  f32x16 acc[2][2] = {};

  auto stage = [&](int buf, int c) {
    const size_t kb = (size_t)(c * 128) + swz;
    char* lb = lds + buf * 73728;
    gload16(gA + (size_t)(w * 8 + lrow8) * (NG * 2) + kb, lb + w * 1024);
    #pragma unroll
    for (int j = 0; j < 8; ++j) {
      const int r = w * 64 + j * 8;
      gload16(gB + (size_t)(r + lrow8) * (NG * 2) + kb, lb + 8192 + r * 128);
    }
  };
  auto compute = [&](int buf) {
    const char* bA = lds + buf * 73728;
    const char* bB = bA + 8192;
    const int swr = (lane & 7) << 4;
    #pragma unroll
    for (int kk = 0; kk < 4; ++kk) {
      const int bc = (kk * 32 + (hi << 4)) ^ swr;
      half8 a0 = *(const half8*)(bA + l31 * 128 + bc);
      half8 a1 = *(const half8*)(bA + (32 + l31) * 128 + bc);
      half8 b0 = *(const half8*)(bB + (w * 64 + l31) * 128 + bc);
      half8 b1 = *(const half8*)(bB + (w * 64 + 32 + l31) * 128 + bc);
      acc[0][0] = mfma16(a0, b0, acc[0][0]);
      acc[0][1] = mfma16(a0, b1, acc[0][1]);
      acc[1][0] = mfma16(a1, b0, acc[1][0]);
      acc[1][1] = mfma16(a1, b1, acc[1][1]);
    }
  };

  stage(0, 0);
  __syncthreads();
  #pragma unroll 1
  for (int c = 0; c < 64; ++c) {
    if (c < 63) stage((c + 1) & 1, c + 1);
    compute(c & 1);
    __syncthreads();
  }

  #pragma unroll
  for (int mf = 0; mf < 2; ++mf) {
    #pragma unroll
    for (int q = 0; q < 16; ++q) {
      float m = fmaxf(acc[mf][0][q], acc[mf][1][q]);
      #pragma unroll
      for (int d = 1; d < 32; d <<= 1) m = fmaxf(m, __shfl_xor(m, d));
      if (l31 == q) redm[w][mf * 32 + (q & 3) + 8 * (q >> 2) + 4 * hi] = m;
    }
  }
  __syncthreads();
  if (tid < 64) {
    float M = redm[0][tid];
    #pragma unroll
    for (int ww = 1; ww < 8; ++ww) M = fmaxf(M, redm[ww][tid]);
    gLS[tid] = M;
  }
  __syncthreads();
  #pragma unroll
  for (int mf = 0; mf < 2; ++mf) {
    #pragma unroll
    for (int q = 0; q < 16; ++q) {
      const int rl = mf * 32 + (q & 3) + 8 * (q >> 2) + 4 * hi;
      const float M = gLS[rl];
      float e = __expf(acc[mf][0][q] - M) + __expf(acc[mf][1][q] - M);
      #pragma unroll
      for (int d = 1; d < 32; d <<= 1) e += __shfl_xor(e, d);
      if (l31 == q) reds[w][rl] = e;
    }
  }
  __syncthreads();
  if (tid < 64) {
    float S = reds[0][tid];
    #pragma unroll
    for (int ww = 1; ww < 8; ++ww) S += reds[ww][tid];
    gLS[tid] = gLS[tid] + __logf(S);
  }
  __syncthreads();
  #pragma unroll
  for (int mf = 0; mf < 2; ++mf) {
    #pragma unroll
    for (int q = 0; q < 16; ++q) {
      const int rl = mf * 32 + (q & 3) + 8 * (q >> 2) + 4 * hi;
      const int r = r0 + rl;
      const int tt = r >> 7, b = r & 127;
      const float lg = gLS[rl];
      float* orow = out + ((size_t)b * NT + tt) * NP + w * 64 + l31;
      orow[0]  = acc[mf][0][q] - lg;
      orow[32] = acc[mf][1][q] - lg;
    }
  }
}

// ---------------- host ----------------

extern "C" void kernel_launch(void* const* d_in, const int* in_sizes, int n_in,
                              void* d_out, int out_size, void* d_ws, size_t ws_size,
                              hipStream_t stream)
{
  const float* v    = (const float*)d_in[0];
  const float* p0   = (const float*)d_in[1];
  const float* wenc = (const float*)d_in[2];
  const float* wih  = (const float*)d_in[3];
  const float* whh  = (const float*)d_in[4];
  const float* wdec = (const float*)d_in[5];
  float* out = (float*)d_out;
  char* ws = (char*)d_ws;

  f16* whh16  = (f16*)(ws);                 // 33,554,432 B
  f16* wdec16 = (f16*)(ws + 33554432);      //  4,194,304 B
  f16* wenc16 = (f16*)(ws + 37748736);      //  4,194,304 B
  f16* p016   = (f16*)(ws + 41943040);      //    131,072 B
  f16* h016   = (f16*)(ws + 42074112);      //  1,048,576 B
  f16* hs     = (f16*)(ws + 43122688);      // 104,857,600 B
  f16* part   = (f16*)d_out;                // 16.8 MB f16 scratch until decode
  const size_t BNG = (size_t)BSZ * NG;

  conv_all<<<dim3(20544), dim3(256), 0, stream>>>(
      whh, wdec, wenc, p0, whh16, wdec16, wenc16, p016);

  // encode: h0 = p0 @ Wenc^T via K-split GEMM (K=512, 2 slices)
  gemm_ksplit<<<dim3(2, 32), dim3(256), 0, stream>>>(wenc16, p016, part, NP, 4);
  reduce_kernel<<<dim3(256), dim3(256), 0, stream>>>(part, v, wih, h016, 0, 2, 0);

  for (int t = 0; t < NT; ++t) {
    const f16* hp = (t == 0) ? h016 : hs + (size_t)(t - 1) * BNG;
    gemm_ksplit<<<dim3(KS, 32), dim3(256), 0, stream>>>(whh16, hp, part, NG, 4);
    reduce_kernel<<<dim3(256), dim3(256), 0, stream>>>(part, v, wih, hs + (size_t)t * BNG, t, KS, 1);
  }
  decode_kernel<<<dim3(200), dim3(512), 0, stream>>>(hs, wdec16, out);
}